// Round 7
// baseline (188.602 us; speedup 1.0000x reference)
//
#include <hip/hip_runtime.h>

// Dims
#define B_   1024
#define S_   128
#define LP_  14
#define K_   3
#define CE_  6
#define WE_  10
#define LF_  4
#define H_   6
#define D_   14
#define T_   135
#define LW_  12
#define V_   50000
#define A_   100
#define SGST 52          // s_g row stride in floats (16B-aligned, spreads banks)

// Fast overflow-safe sigmoid/tanh (inf-propagation gives correct saturation).
static __device__ __forceinline__ float fsigm(float x) {
    return __frcp_rn(1.0f + __expf(-x));
}
static __device__ __forceinline__ float ftanh(float x) {
    return fmaf(2.0f, __frcp_rn(1.0f + __expf(-2.0f * x)), -1.0f);
}

// Wave64 all-lane sum via DPP (no DS traffic).
static __device__ __forceinline__ float wave_sum64(float s) {
    int v = __float_as_int(s);
    float f;
    f = __int_as_float(__builtin_amdgcn_update_dpp(0, v, 0xB1, 0xF, 0xF, true));  s += f; v = __float_as_int(s);
    f = __int_as_float(__builtin_amdgcn_update_dpp(0, v, 0x4E, 0xF, 0xF, true));  s += f; v = __float_as_int(s);
    f = __int_as_float(__builtin_amdgcn_update_dpp(0, v, 0x141, 0xF, 0xF, true)); s += f; v = __float_as_int(s);
    f = __int_as_float(__builtin_amdgcn_update_dpp(0, v, 0x140, 0xF, 0xF, true)); s += f; v = __float_as_int(s);
    f = __int_as_float(__builtin_amdgcn_update_dpp(0, v, 0x142, 0xA, 0xF, true)); s += f; v = __float_as_int(s);
    f = __int_as_float(__builtin_amdgcn_update_dpp(0, v, 0x143, 0xC, 0xF, true)); s += f; v = __float_as_int(s);
    return __int_as_float(__builtin_amdgcn_readlane(v, 63));
}

// ---------------- Kernel 1 (fused): char CNN + embeddings + gate preacts + BiLSTM ----------
// Block = ONE sentence, 128 threads = 2 waves. LDS-only dataflow (no gbuf round-trip,
// no global-load pipelining problem -- the R2-R6 dead end).
// Phase E: thread t = word t: char CNN + word emb + BOTH directions' 24 gate preacts
//          -> s_g[t][0..23] (fwd), s_g[t][24..47] (bwd). Stride 52 floats (16B-aligned).
// Phase L: wave 0 = forward, wave 1 = backward. Lanes 0-5 = units (6-63 shadow u=5).
//          Per step: one LDS float4 (prefetched 1 step ahead, ~120cy << step compute),
//          24 FMA, 4 activations, 6 readlane (dir wave-uniform -> no selects). No VMEM.
// 1024 blocks, 4/CU (LDS ~36KB), E of some blocks overlaps L of others.
__global__ __launch_bounds__(128, 2) void k_f(
    const int* __restrict__ word_idx, const int* __restrict__ char_idx,
    const float* __restrict__ word_emb, const float* __restrict__ char_emb,
    const float* __restrict__ Wc, const float* __restrict__ bc,
    const float* __restrict__ Wih_f, const float* __restrict__ Whh_f, const float* __restrict__ b_f,
    const float* __restrict__ Wih_b, const float* __restrict__ Whh_b, const float* __restrict__ b_b,
    float* __restrict__ hbuf)
{
    __shared__ __align__(16) float s_g[S_][SGST];   // 26.6 KB gate preacts
    __shared__ __align__(16) float s_h[S_][12];     // 6 KB outputs
    __shared__ float s_ce[A_ * CE_];                // 2.4 KB
    __shared__ float s_wc[LF_ * K_ * CE_];
    __shared__ float s_bc[LF_];

    int t = threadIdx.x;
    int b = blockIdx.x;

    for (int e = t; e < A_ * CE_; e += 128) s_ce[e] = char_emb[e];
    if (t < LF_ * K_ * CE_) s_wc[t] = Wc[t];
    if (t < LF_) s_bc[t] = bc[t];
    __syncthreads();

    // ---- Phase E: thread t = word step t of sentence b ----
    {
        int w = b * S_ + t;
        const int2* ci2 = (const int2*)(char_idx + (size_t)w * LP_);   // w*56B, 8B-aligned
        int idxs[LP_];
        #pragma unroll
        for (int p = 0; p < 7; ++p) {
            int2 v = ci2[p];
            idxs[2 * p] = v.x; idxs[2 * p + 1] = v.y;
        }
        float ce[LP_][CE_];
        #pragma unroll
        for (int p = 0; p < LP_; ++p) {
            int idx = idxs[p];
            idx = idx < 0 ? 0 : (idx >= A_ ? A_ - 1 : idx);
            #pragma unroll
            for (int c = 0; c < CE_; ++c) ce[p][c] = s_ce[idx * CE_ + c];
        }
        float x[D_];
        #pragma unroll
        for (int l = 0; l < LF_; ++l) {
            float acc[LW_];
            float bl = s_bc[l];
            #pragma unroll
            for (int q = 0; q < LW_; ++q) acc[q] = bl;
            #pragma unroll
            for (int kk = 0; kk < K_; ++kk) {
                #pragma unroll
                for (int c = 0; c < CE_; ++c) {
                    float wv_ = s_wc[l * (K_ * CE_) + kk * CE_ + c];
                    #pragma unroll
                    for (int q = 0; q < LW_; ++q) acc[q] = fmaf(ce[q + kk][c], wv_, acc[q]);
                }
            }
            float m = acc[0];
            #pragma unroll
            for (int q = 1; q < LW_; ++q) m = fmaxf(m, acc[q]);
            x[WE_ + l] = m;
        }
        int wi = word_idx[w];
        wi = wi < 0 ? 0 : (wi >= V_ ? V_ - 1 : wi);
        const float2* wep = (const float2*)(word_emb + (size_t)wi * WE_);  // wi*40B, 8B-aligned
        #pragma unroll
        for (int c = 0; c < WE_ / 2; ++c) {
            float2 v = wep[c];
            x[2 * c] = v.x; x[2 * c + 1] = v.y;
        }

        // Gate preacts (weights wave-uniform -> scalar loads). float4 #u = (i,f,g,o) of unit u.
        float4* dstf = (float4*)&s_g[t][0];
        {
            float g[24];
            #pragma unroll
            for (int r = 0; r < 24; ++r) {
                float a = b_f[r];
                #pragma unroll
                for (int k = 0; k < D_; ++k) a = fmaf(Wih_f[r * D_ + k], x[k], a);
                g[r] = a;
            }
            #pragma unroll
            for (int u = 0; u < H_; ++u)
                dstf[u] = make_float4(g[u], g[H_ + u], g[2 * H_ + u], g[3 * H_ + u]);
        }
        float4* dstb = (float4*)&s_g[t][24];
        {
            float g[24];
            #pragma unroll
            for (int r = 0; r < 24; ++r) {
                float a = b_b[r];
                #pragma unroll
                for (int k = 0; k < D_; ++k) a = fmaf(Wih_b[r * D_ + k], x[k], a);
                g[r] = a;
            }
            #pragma unroll
            for (int u = 0; u < H_; ++u)
                dstb[u] = make_float4(g[u], g[H_ + u], g[2 * H_ + u], g[3 * H_ + u]);
        }
    }
    __syncthreads();

    // ---- Phase L: wave 0 = fwd, wave 1 = bwd; lanes 0-5 = units ----
    {
        int wv   = t >> 6;                    // direction, wave-uniform
        int lane = t & 63;
        bool act = (lane < H_);
        int u    = act ? lane : (H_ - 1);

        const float* Whh = wv ? Whh_b : Whh_f;
        float w0[H_], w1[H_], w2[H_], w3[H_];
        #pragma unroll
        for (int k = 0; k < H_; ++k) {
            w0[k] = Whh[(0 * H_ + u) * H_ + k];
            w1[k] = Whh[(1 * H_ + u) * H_ + k];
            w2[k] = Whh[(2 * H_ + u) * H_ + k];
            w3[k] = Whh[(3 * H_ + u) * H_ + k];
        }

        const float* gp = &s_g[wv ? (S_ - 1) : 0][wv * 24 + u * 4];
        const int gstep = wv ? -SGST : SGST;

        float h[H_];
        #pragma unroll
        for (int k = 0; k < H_; ++k) h[k] = 0.f;
        float c = 0.f;

        float4 g4 = *(const float4*)gp;

#define LSTEP(G4, J)                                                            \
        {                                                                       \
            float ai = (G4).x, af = (G4).y, ag = (G4).z, ao = (G4).w;           \
            _Pragma("unroll")                                                   \
            for (int k = 0; k < H_; ++k) {                                      \
                ai = fmaf(w0[k], h[k], ai);                                     \
                af = fmaf(w1[k], h[k], af);                                     \
                ag = fmaf(w2[k], h[k], ag);                                     \
                ao = fmaf(w3[k], h[k], ao);                                     \
            }                                                                   \
            float si = fsigm(ai), sf = fsigm(af), so = fsigm(ao), tg = ftanh(ag); \
            c = fmaf(sf, c, si * tg);                                           \
            float hu = so * ftanh(c);                                           \
            int se = wv ? (S_ - 1 - (J)) : (J);                                 \
            if (act) s_h[se][wv * H_ + u] = hu;                                 \
            _Pragma("unroll")                                                   \
            for (int k = 0; k < H_; ++k)                                        \
                h[k] = __int_as_float(__builtin_amdgcn_readlane(__float_as_int(hu), k)); \
        }

        #pragma unroll 4
        for (int j = 0; j < S_ - 1; ++j) {
            gp += gstep;
            float4 nx = *(const float4*)gp;   // prefetch j+1 (LDS, hides under compute)
            LSTEP(g4, j);
            g4 = nx;
        }
        LSTEP(g4, S_ - 1);
#undef LSTEP
    }
    __syncthreads();

    // ---- epilogue: s_h -> hbuf coalesced: 128*12 floats = 384 float4 ----
    {
        float4* dst = (float4*)(hbuf + (size_t)b * S_ * 12);
        const float4* src = (const float4*)&s_h[0][0];
        #pragma unroll
        for (int i = 0; i < 3; ++i) dst[t + 128 * i] = src[t + 128 * i];
    }
}

// ---------------- Kernel 2: projection + log_softmax -> out f32 [B*S][135] ----------------
__global__ __launch_bounds__(256) void k_p(
    const float* __restrict__ hbuf,
    const float* __restrict__ Wt, const float* __restrict__ bt,
    float* __restrict__ out)
{
    __shared__ float s_hb[64 * 12];         // 3 KB
    int t = threadIdx.x;
    int ib = blockIdx.x * 64;               // first item of block
    {
        const float4* src = (const float4*)(hbuf + (size_t)ib * 12);
        float4* dst = (float4*)s_hb;
        if (t < 192) dst[t] = src[t];       // 64*12 floats = 192 float4, coalesced
    }
    __syncthreads();

    int lane = t & 63, wv = t >> 6;
    bool has2 = (lane < T_ - 128);
    int t2c = has2 ? (lane + 128) : (T_ - 1);

    float wA[12], wB[12], wC[12];
    #pragma unroll
    for (int jj = 0; jj < 12; ++jj) {
        wA[jj] = Wt[lane * 12 + jj];
        wB[jj] = Wt[(lane + 64) * 12 + jj];
        wC[jj] = Wt[t2c * 12 + jj];
    }
    float bA = bt[lane], bB = bt[lane + 64], bC = bt[t2c];

    int it0 = wv * 16;
    #pragma unroll 4
    for (int k = 0; k < 16; ++k) {
        int it = it0 + k;
        const float4* h4 = (const float4*)(s_hb + it * 12);   // broadcast LDS reads
        float4 a0 = h4[0], a1 = h4[1], a2 = h4[2];
        float hv[12] = {a0.x, a0.y, a0.z, a0.w, a1.x, a1.y, a1.z, a1.w, a2.x, a2.y, a2.z, a2.w};
        float y0 = bA, y1 = bB, y2 = bC;
        #pragma unroll
        for (int jj = 0; jj < 12; ++jj) {
            y0 = fmaf(hv[jj], wA[jj], y0);
            y1 = fmaf(hv[jj], wB[jj], y1);
            y2 = fmaf(hv[jj], wC[jj], y2);
        }
        // |y| small (h in (-1,1), weights ~0.1) -> exp safe without max-subtraction
        float ss = __expf(y0) + __expf(y1) + (has2 ? __expf(y2) : 0.0f);
        float ls = __logf(wave_sum64(ss));
        float* op = out + (size_t)(ib + it) * T_;
        op[lane]      = y0 - ls;
        op[lane + 64] = y1 - ls;
        if (has2) op[lane + 128] = y2 - ls;
    }
}

extern "C" void kernel_launch(void* const* d_in, const int* in_sizes, int n_in,
                              void* d_out, int out_size, void* d_ws, size_t ws_size,
                              hipStream_t stream)
{
    const int* word_idx = (const int*)d_in[0];
    const int* char_idx = (const int*)d_in[1];
    const float* word_emb = (const float*)d_in[2];
    const float* char_emb = (const float*)d_in[3];
    const float* Wc    = (const float*)d_in[4];
    const float* bc    = (const float*)d_in[5];
    const float* Wih_f = (const float*)d_in[6];
    const float* Whh_f = (const float*)d_in[7];
    const float* b_f   = (const float*)d_in[8];
    const float* Wih_b = (const float*)d_in[9];
    const float* Whh_b = (const float*)d_in[10];
    const float* b_b   = (const float*)d_in[11];
    const float* Wt    = (const float*)d_in[12];
    const float* bt    = (const float*)d_in[13];

    float* hbuf = (float*)d_ws;    // B*S*12 f32 = 6.3 MB (only workspace use now)

    k_f<<<B_, 128, 0, stream>>>(word_idx, char_idx, word_emb, char_emb, Wc, bc,
                                Wih_f, Whh_f, b_f, Wih_b, Whh_b, b_b, hbuf);
    k_p<<<(B_ * S_) / 64, 256, 0, stream>>>(hbuf, Wt, bt, (float*)d_out);
}

// Round 8
// 175.743 us; speedup vs baseline: 1.0732x; 1.0732x over previous
//
#include <hip/hip_runtime.h>

// Dims
#define B_   1024
#define S_   128
#define LP_  14
#define K_   3
#define CE_  6
#define WE_  10
#define LF_  4
#define H_   6
#define D_   14
#define T_   135
#define LW_  12
#define V_   50000
#define A_   100
#define SGST 52          // s_g row stride in floats (16B-aligned; 52 mod 32 = 20 spreads banks)

// Fast sigmoid/tanh: single v_rcp_f32 (1ulp) instead of __frcp_rn's div_scale/div_fmas/
// div_fixup sequence (~10 inst, long serial chain). Saturation exact: rcp(1)=1, rcp(inf)=0.
static __device__ __forceinline__ float fsigm(float x) {
    return __builtin_amdgcn_rcpf(1.0f + __expf(-x));
}
static __device__ __forceinline__ float ftanh(float x) {
    return fmaf(2.0f, __builtin_amdgcn_rcpf(1.0f + __expf(-2.0f * x)), -1.0f);
}

// Wave64 all-lane sum via DPP (no DS traffic).
static __device__ __forceinline__ float wave_sum64(float s) {
    int v = __float_as_int(s);
    float f;
    f = __int_as_float(__builtin_amdgcn_update_dpp(0, v, 0xB1, 0xF, 0xF, true));  s += f; v = __float_as_int(s);
    f = __int_as_float(__builtin_amdgcn_update_dpp(0, v, 0x4E, 0xF, 0xF, true));  s += f; v = __float_as_int(s);
    f = __int_as_float(__builtin_amdgcn_update_dpp(0, v, 0x141, 0xF, 0xF, true)); s += f; v = __float_as_int(s);
    f = __int_as_float(__builtin_amdgcn_update_dpp(0, v, 0x140, 0xF, 0xF, true)); s += f; v = __float_as_int(s);
    f = __int_as_float(__builtin_amdgcn_update_dpp(0, v, 0x142, 0xA, 0xF, true)); s += f; v = __float_as_int(s);
    f = __int_as_float(__builtin_amdgcn_update_dpp(0, v, 0x143, 0xC, 0xF, true)); s += f; v = __float_as_int(s);
    return __int_as_float(__builtin_amdgcn_readlane(v, 63));
}

// Group-of-8 lane broadcast: every lane receives the value held by lane (group_base | k).
// ds_swizzle BitMode: new_lane = ((lane & and) | or) ^ xor ; offset = (xor<<10)|(or<<5)|and.
// and = 0x18 keeps the group bits; or = k selects the unit. Pattern-uniform across groups.
#define GBCAST(dst, src, kk) \
    dst = __int_as_float(__builtin_amdgcn_ds_swizzle(__float_as_int(src), 0x18 | ((kk) << 5)))

// ---------------- Kernel 1 (fused): char CNN + embeddings + gate preacts + BiLSTM ----------
// Block = TWO sentences, 128 threads = 2 waves, grid 512, 2 blocks/CU (LDS ~68 KB).
// Phase E: thread handles 2 words (one per sentence): char CNN + word emb + both dirs'
//          24 gate preacts -> s_g[sent][step][48] (stride 52).
// Phase L: wave = direction. 8-lane groups: lanes 0-7 = sent0, 8-15 = sent1 (lanes 16-63
//          shadow sent1). Lane = unit u of its group's sequence, owns all 4 gates ->
//          c-update lane-local. Per step: 1 ds_read_b128 (prefetched 1 ahead), 24 FMA,
//          5 fast activations, 6 ds_swizzle group-broadcasts, 1 exec-masked ds_write.
//          4 sequences per wave amortize the wave's instruction stream 4x vs R7 (whose
//          counters showed VALU-issue saturation: VALUBusy 68% with 58/64 shadow lanes).
__global__ __launch_bounds__(128, 2) void k_f(
    const int* __restrict__ word_idx, const int* __restrict__ char_idx,
    const float* __restrict__ word_emb, const float* __restrict__ char_emb,
    const float* __restrict__ Wc, const float* __restrict__ bc,
    const float* __restrict__ Wih_f, const float* __restrict__ Whh_f, const float* __restrict__ b_f,
    const float* __restrict__ Wih_b, const float* __restrict__ Whh_b, const float* __restrict__ b_b,
    float* __restrict__ hbuf)
{
    __shared__ __align__(16) float s_g[2][S_][SGST];   // 53.2 KB gate preacts
    __shared__ __align__(16) float s_h[2][S_][12];     // 12.3 KB outputs
    __shared__ float s_ce[A_ * CE_];                   // 2.4 KB
    __shared__ float s_wc[LF_ * K_ * CE_];
    __shared__ float s_bc[LF_];

    int t = threadIdx.x;
    int blk = blockIdx.x;

    for (int e = t; e < A_ * CE_; e += 128) s_ce[e] = char_emb[e];
    if (t < LF_ * K_ * CE_) s_wc[t] = Wc[t];
    if (t < LF_) s_bc[t] = bc[t];
    __syncthreads();

    // ---- Phase E: rep = sentence-in-block, thread t = word step t ----
    #pragma unroll
    for (int rep = 0; rep < 2; ++rep) {
        int sent = rep;
        int step = t;
        int w = (blk * 2 + sent) * S_ + step;

        const int2* ci2 = (const int2*)(char_idx + (size_t)w * LP_);   // w*56B, 8B-aligned
        int idxs[LP_];
        #pragma unroll
        for (int p = 0; p < 7; ++p) {
            int2 v = ci2[p];
            idxs[2 * p] = v.x; idxs[2 * p + 1] = v.y;
        }
        float ce[LP_][CE_];
        #pragma unroll
        for (int p = 0; p < LP_; ++p) {
            int idx = idxs[p];
            idx = idx < 0 ? 0 : (idx >= A_ ? A_ - 1 : idx);
            #pragma unroll
            for (int c = 0; c < CE_; ++c) ce[p][c] = s_ce[idx * CE_ + c];
        }
        float x[D_];
        #pragma unroll
        for (int l = 0; l < LF_; ++l) {
            float acc[LW_];
            float bl = s_bc[l];
            #pragma unroll
            for (int q = 0; q < LW_; ++q) acc[q] = bl;
            #pragma unroll
            for (int kk = 0; kk < K_; ++kk) {
                #pragma unroll
                for (int c = 0; c < CE_; ++c) {
                    float wv_ = s_wc[l * (K_ * CE_) + kk * CE_ + c];
                    #pragma unroll
                    for (int q = 0; q < LW_; ++q) acc[q] = fmaf(ce[q + kk][c], wv_, acc[q]);
                }
            }
            float m = acc[0];
            #pragma unroll
            for (int q = 1; q < LW_; ++q) m = fmaxf(m, acc[q]);
            x[WE_ + l] = m;
        }
        int wi = word_idx[w];
        wi = wi < 0 ? 0 : (wi >= V_ ? V_ - 1 : wi);
        const float2* wep = (const float2*)(word_emb + (size_t)wi * WE_);  // wi*40B, 8B-aligned
        #pragma unroll
        for (int c = 0; c < WE_ / 2; ++c) {
            float2 v = wep[c];
            x[2 * c] = v.x; x[2 * c + 1] = v.y;
        }

        // Gate preacts (weights wave-uniform -> scalar loads). float4 #u = (i,f,g,o) of unit u.
        float4* dstf = (float4*)&s_g[sent][step][0];
        {
            float g[24];
            #pragma unroll
            for (int r = 0; r < 24; ++r) {
                float a = b_f[r];
                #pragma unroll
                for (int k = 0; k < D_; ++k) a = fmaf(Wih_f[r * D_ + k], x[k], a);
                g[r] = a;
            }
            #pragma unroll
            for (int u = 0; u < H_; ++u)
                dstf[u] = make_float4(g[u], g[H_ + u], g[2 * H_ + u], g[3 * H_ + u]);
        }
        float4* dstb = (float4*)&s_g[sent][step][24];
        {
            float g[24];
            #pragma unroll
            for (int r = 0; r < 24; ++r) {
                float a = b_b[r];
                #pragma unroll
                for (int k = 0; k < D_; ++k) a = fmaf(Wih_b[r * D_ + k], x[k], a);
                g[r] = a;
            }
            #pragma unroll
            for (int u = 0; u < H_; ++u)
                dstb[u] = make_float4(g[u], g[H_ + u], g[2 * H_ + u], g[3 * H_ + u]);
        }
    }
    __syncthreads();

    // ---- Phase L: wave = direction; 8-lane groups = sequences; lane = unit ----
    {
        int dir  = t >> 6;                      // wave-uniform
        int lane = t & 63;
        int grp  = lane >> 3;
        int sent = (grp < 2) ? grp : 1;         // shadow lanes clamp to sent1 (same-addr bcast)
        int u8   = lane & 7;
        int u    = (u8 < H_) ? u8 : (H_ - 1);
        bool act = (lane < 16) && (u8 < H_);

        const float* Whh = dir ? Whh_b : Whh_f;
        float w0[H_], w1[H_], w2[H_], w3[H_];
        #pragma unroll
        for (int k = 0; k < H_; ++k) {
            w0[k] = Whh[(0 * H_ + u) * H_ + k];
            w1[k] = Whh[(1 * H_ + u) * H_ + k];
            w2[k] = Whh[(2 * H_ + u) * H_ + k];
            w3[k] = Whh[(3 * H_ + u) * H_ + k];
        }

        const float* gp = &s_g[sent][dir ? (S_ - 1) : 0][dir * 24 + u * 4];
        const int gstep = dir ? -SGST : SGST;
        float* hp = &s_h[sent][dir ? (S_ - 1) : 0][dir * H_ + u];
        const int hstep = dir ? -12 : 12;

        float h[H_];
        #pragma unroll
        for (int k = 0; k < H_; ++k) h[k] = 0.f;
        float c = 0.f;

        float4 g4 = *(const float4*)gp;

#define LSTEP(G4)                                                               \
        {                                                                       \
            float ai = (G4).x, af = (G4).y, ag = (G4).z, ao = (G4).w;           \
            _Pragma("unroll")                                                   \
            for (int k = 0; k < H_; ++k) {                                      \
                ai = fmaf(w0[k], h[k], ai);                                     \
                af = fmaf(w1[k], h[k], af);                                     \
                ag = fmaf(w2[k], h[k], ag);                                     \
                ao = fmaf(w3[k], h[k], ao);                                     \
            }                                                                   \
            float si = fsigm(ai), sf = fsigm(af), so = fsigm(ao), tg = ftanh(ag); \
            c = fmaf(sf, c, si * tg);                                           \
            float hu = so * ftanh(c);                                           \
            if (act) *hp = hu;                                                  \
            hp += hstep;                                                        \
            GBCAST(h[0], hu, 0); GBCAST(h[1], hu, 1); GBCAST(h[2], hu, 2);      \
            GBCAST(h[3], hu, 3); GBCAST(h[4], hu, 4); GBCAST(h[5], hu, 5);      \
        }

        #pragma unroll 4
        for (int j = 0; j < S_ - 1; ++j) {
            gp += gstep;
            float4 nx = *(const float4*)gp;   // prefetch j+1 (LDS, hides under compute)
            LSTEP(g4);
            g4 = nx;
        }
        LSTEP(g4);
#undef LSTEP
    }
    __syncthreads();

    // ---- epilogue: s_h -> hbuf coalesced: 2*128*12 floats = 768 float4 ----
    {
        float4* dst = (float4*)(hbuf + (size_t)blk * 2 * S_ * 12);
        const float4* src = (const float4*)&s_h[0][0][0];
        #pragma unroll
        for (int i = 0; i < 6; ++i) dst[t + 128 * i] = src[t + 128 * i];
    }
}

// ---------------- Kernel 2: projection + log_softmax -> out f32 [B*S][135] ----------------
__global__ __launch_bounds__(256) void k_p(
    const float* __restrict__ hbuf,
    const float* __restrict__ Wt, const float* __restrict__ bt,
    float* __restrict__ out)
{
    __shared__ float s_hb[64 * 12];         // 3 KB
    int t = threadIdx.x;
    int ib = blockIdx.x * 64;               // first item of block
    {
        const float4* src = (const float4*)(hbuf + (size_t)ib * 12);
        float4* dst = (float4*)s_hb;
        if (t < 192) dst[t] = src[t];       // 64*12 floats = 192 float4, coalesced
    }
    __syncthreads();

    int lane = t & 63, wv = t >> 6;
    bool has2 = (lane < T_ - 128);
    int t2c = has2 ? (lane + 128) : (T_ - 1);

    float wA[12], wB[12], wC[12];
    #pragma unroll
    for (int jj = 0; jj < 12; ++jj) {
        wA[jj] = Wt[lane * 12 + jj];
        wB[jj] = Wt[(lane + 64) * 12 + jj];
        wC[jj] = Wt[t2c * 12 + jj];
    }
    float bA = bt[lane], bB = bt[lane + 64], bC = bt[t2c];

    int it0 = wv * 16;
    #pragma unroll 4
    for (int k = 0; k < 16; ++k) {
        int it = it0 + k;
        const float4* h4 = (const float4*)(s_hb + it * 12);   // broadcast LDS reads
        float4 a0 = h4[0], a1 = h4[1], a2 = h4[2];
        float hv[12] = {a0.x, a0.y, a0.z, a0.w, a1.x, a1.y, a1.z, a1.w, a2.x, a2.y, a2.z, a2.w};
        float y0 = bA, y1 = bB, y2 = bC;
        #pragma unroll
        for (int jj = 0; jj < 12; ++jj) {
            y0 = fmaf(hv[jj], wA[jj], y0);
            y1 = fmaf(hv[jj], wB[jj], y1);
            y2 = fmaf(hv[jj], wC[jj], y2);
        }
        // |y| small (h in (-1,1), weights ~0.1) -> exp safe without max-subtraction
        float ss = __expf(y0) + __expf(y1) + (has2 ? __expf(y2) : 0.0f);
        float ls = __logf(wave_sum64(ss));
        float* op = out + (size_t)(ib + it) * T_;
        op[lane]      = y0 - ls;
        op[lane + 64] = y1 - ls;
        if (has2) op[lane + 128] = y2 - ls;
    }
}

extern "C" void kernel_launch(void* const* d_in, const int* in_sizes, int n_in,
                              void* d_out, int out_size, void* d_ws, size_t ws_size,
                              hipStream_t stream)
{
    const int* word_idx = (const int*)d_in[0];
    const int* char_idx = (const int*)d_in[1];
    const float* word_emb = (const float*)d_in[2];
    const float* char_emb = (const float*)d_in[3];
    const float* Wc    = (const float*)d_in[4];
    const float* bc    = (const float*)d_in[5];
    const float* Wih_f = (const float*)d_in[6];
    const float* Whh_f = (const float*)d_in[7];
    const float* b_f   = (const float*)d_in[8];
    const float* Wih_b = (const float*)d_in[9];
    const float* Whh_b = (const float*)d_in[10];
    const float* b_b   = (const float*)d_in[11];
    const float* Wt    = (const float*)d_in[12];
    const float* bt    = (const float*)d_in[13];

    float* hbuf = (float*)d_ws;    // B*S*12 f32 = 6.3 MB (only workspace use)

    k_f<<<B_ / 2, 128, 0, stream>>>(word_idx, char_idx, word_emb, char_emb, Wc, bc,
                                    Wih_f, Whh_f, b_f, Wih_b, Whh_b, b_b, hbuf);
    k_p<<<(B_ * S_) / 64, 256, 0, stream>>>(hbuf, Wt, bt, (float*)d_out);
}